// Round 8
// baseline (839.972 us; speedup 1.0000x reference)
//
#include <hip/hip_runtime.h>
#include <hip/hip_bf16.h>
#include <math.h>

typedef __attribute__((ext_vector_type(8))) short short8;
typedef __attribute__((ext_vector_type(4))) float f32x4;

#define KN 100
#define ITERS 16

// ---- ws layout (halfword units) ----
// Weights stored as A-fragments with k-slot permutation sigma(quad,s):
//   element index i = 32*k4 + 16*(s>>2) + 4*quad + (s&3)
// scr rows stored column-PERMUTED with matching P(): position
//   p = 32*k4 + 8*quad + s  holds element j = 32*k4 + 16*(s>>2) + 4*quad + (s&3)
// P maps {0..99} onto {0..99} and {100..127} onto {100..127}: per Et row the
// staged bytes are exactly hw 0..99 and pad is exactly hw 100..127.
#define W1_OFF 0         // 64x128 bf16, kt=4
#define W2_OFF 8192      // 64x64,  kt=2
#define W3_OFF 12288     // 32x64,  kt=2
#define W4_OFF 14336     // 32x32,  kt=1  (stays in GLOBAL; not staged to LDS)
#define SCRU_OFF 16384                        // 100000 x 128 bf16 (P-permuted, zero-pad j>=100)
#define SCRI_OFF (SCRU_OFF + 100000 * 128)    // 50000 x 128
#define EMBU_OFF (SCRI_OFF + 50000 * 128)     // 100000 x 64 bf16
#define EMBI_OFF (EMBU_OFF + 100000 * 64)     // 50000 x 64

// ---- LDS (halfword offsets): [W1..W3 14336][ETU 8704][ETI 8704]
// = 31744 hw = 63488 B -> 2 blocks/CU. Row stride 136 hw; chunk swizzle:
// hw offset p ^= ((row>>3)&7)<<3 on both store and read.
#define ET_STRIDE 136
#define ETU_OFF 14336
#define ETI_OFF (14336 + 64 * ET_STRIDE)
#define S_TOT   (14336 + 2 * 64 * ET_STRIDE)   // 31744 hw

__device__ __forceinline__ unsigned short f2bf(float f) {
  __hip_bfloat16 h = __float2bfloat16(f);
  return __builtin_bit_cast(unsigned short, h);
}

__device__ __forceinline__ void st8(unsigned short* d, float4 a, float4 b) {
  short8 h;
  h[0] = (short)f2bf(a.x); h[1] = (short)f2bf(a.y);
  h[2] = (short)f2bf(a.z); h[3] = (short)f2bf(a.w);
  h[4] = (short)f2bf(b.x); h[5] = (short)f2bf(b.y);
  h[6] = (short)f2bf(b.z); h[7] = (short)f2bf(b.w);
  *reinterpret_cast<short8*>(d) = h;
}

__device__ __forceinline__ short8 pk2(f32x4 a, f32x4 b) {
  short8 h;
  h[0] = (short)f2bf(a[0]); h[1] = (short)f2bf(a[1]);
  h[2] = (short)f2bf(a[2]); h[3] = (short)f2bf(a[3]);
  h[4] = (short)f2bf(b[0]); h[5] = (short)f2bf(b[1]);
  h[6] = (short)f2bf(b[2]); h[7] = (short)f2bf(b[3]);
  return h;
}

// Streaming prep (grid-stride): unchanged (verified r4-r7).
#define PREP_UNITS (15360 + 2400000 + 1200000)
__global__ void prep(const float* __restrict__ w1, const float* __restrict__ w2,
                     const float* __restrict__ w3, const float* __restrict__ w4,
                     const float* __restrict__ uscr, const float* __restrict__ iscr,
                     const float* __restrict__ uemb, const float* __restrict__ iemb,
                     unsigned short* __restrict__ ws) {
  const float4 z4 = {0.f, 0.f, 0.f, 0.f};
  const int stride = gridDim.x * 256;
  for (int t = blockIdx.x * 256 + threadIdx.x; t < PREP_UNITS; t += stride) {
    if (t < 15360) {
      const float* src; int rel, o, i, kt, base;
      if (t < 8192)       { src = w1; rel = t;         o = rel >> 7; i = rel & 127; kt = 4; base = W1_OFF; }
      else if (t < 12288) { src = w2; rel = t - 8192;  o = rel >> 6; i = rel & 63;  kt = 2; base = W2_OFF; }
      else if (t < 14336) { src = w3; rel = t - 12288; o = rel >> 6; i = rel & 63;  kt = 2; base = W3_OFF; }
      else                { src = w4; rel = t - 14336; o = rel >> 5; i = rel & 31;  kt = 1; base = W4_OFF; }
      int n = o >> 4, l15 = o & 15, k = i >> 5;
      int quad = (i >> 2) & 3, s = ((i >> 4) & 1) * 4 + (i & 3);
      ws[base + ((n * kt + k) * 64 + quad * 16 + l15) * 8 + s] = f2bf(src[rel]);
      continue;
    }
    int rel = t - 15360;
    if (rel < 2400000) {  // scr: 16 threads/row, 8 outputs each (P-permuted)
      const float* src; unsigned short* dst; int row, g;
      if (rel < 1600000) {
        row = rel >> 4; g = rel & 15;
        src = uscr + (size_t)row * 100;
        dst = ws + SCRU_OFF + (size_t)row * 128 + g * 8;
      } else {
        int q = rel - 1600000; row = q >> 4; g = q & 15;
        src = iscr + (size_t)row * 100;
        dst = ws + SCRI_OFF + (size_t)row * 128 + g * 8;
      }
      const int jb = 32 * (g >> 2) + 4 * (g & 3);
      float4 va = (jb <= 96) ? *reinterpret_cast<const float4*>(src + jb) : z4;
      float4 vb = (jb <= 80) ? *reinterpret_cast<const float4*>(src + jb + 16) : z4;
      st8(dst, va, vb);
      continue;
    }
    rel -= 2400000;
    {  // emb: 8 threads/row, 8 outputs each (64 cols)
      const float* src; unsigned short* dst; int row, g;
      if (rel < 800000) {
        row = rel >> 3; g = rel & 7;
        src = uemb + (size_t)row * 64;
        dst = ws + EMBU_OFF + (size_t)row * 64 + g * 8;
      } else {
        int q = rel - 800000; row = q >> 3; g = q & 7;
        src = iemb + (size_t)row * 64;
        dst = ws + EMBI_OFF + (size_t)row * 64 + g * 8;
      }
      float4 va = *reinterpret_cast<const float4*>(src + g * 8);
      float4 vb = *reinterpret_cast<const float4*>(src + g * 8 + 4);
      st8(dst, va, vb);
    }
  }
}

// Pool MFMA for one source: acc = X^T tiles (lane = m, regs = feature rows).
__device__ __forceinline__ void pool_mfma(const unsigned short* __restrict__ Sb,
                                          const short8* sb, int l15, int quad,
                                          short8& f0, short8& f1) {
  f32x4 acc[4];
#pragma unroll
  for (int po = 0; po < 4; ++po) acc[po] = (f32x4){0.f, 0.f, 0.f, 0.f};
#pragma unroll
  for (int k4 = 0; k4 < 4; ++k4) {
#pragma unroll
    for (int po = 0; po < 4; ++po) {
      const int row = po * 16 + l15;
      const int hw = row * ET_STRIDE + (((k4 * 4 + quad) ^ ((row >> 3) & 7)) << 3);
      short8 ea = *reinterpret_cast<const short8*>(Sb + hw);
      acc[po] = __builtin_amdgcn_mfma_f32_16x16x32_bf16(ea, sb[k4], acc[po], 0, 0, 0);
    }
  }
  f0 = pk2(acc[0], acc[1]);
  f1 = pk2(acc[2], acc[3]);
}

// Et staging from pre-gathered registers (u32-paired via shfl_xor across
// halves, chunk-swizzled addresses). Writes only logical hw 0..99 per row.
__device__ __forceinline__ void et_store(unsigned short* __restrict__ S,
                                         const unsigned int* ev, int w, int c,
                                         int half, int base) {
#pragma unroll
  for (int rr = 0; rr < 8; ++rr) {
    const int rbase = w + rr * 7;
    if (rbase < 50) {
      const int r0 = rbase * 2;
      const int p0 = ((r0 >> 5) << 5) | (((r0 >> 2) & 3) << 3) |
                     (((r0 >> 4) & 1) << 2) | (r0 & 3);  // even
      const int sw = ((c >> 2) & 7) << 3;  // = ((row>>3)&7)<<3 for both halves
      const int q = (2 * c + half) * ET_STRIDE + (p0 ^ sw);  // even hw offset
      unsigned int v = ev[rr];
      unsigned int p = __shfl_xor(v, 32, 64);
      unsigned int d = half ? ((v & 0xffff0000u) | (p >> 16))
                            : ((v & 0x0000ffffu) | (p << 16));
      *reinterpret_cast<unsigned int*>(&S[base + q]) = d;
    }
  }
}

// Per-lane idx loads for batch element b (broadcast-addressed, L1-hot after
// first wave). rbase<50 guard is wave-uniform.
__device__ __forceinline__ void load_idx(
    int b, int w, int half, int mrow,
    const int* __restrict__ user_idx_t, const int* __restrict__ item_idx_t,
    const int* __restrict__ user_idxs, const int* __restrict__ item_idxs,
    int* nbu_e, int* nbi_e, int& nbu_m, int& nbi_m) {
  const int ub = user_idxs[b] * KN;
  const int ibx = item_idxs[b] * KN;
#pragma unroll
  for (int rr = 0; rr < 8; ++rr) {
    const int rbase = w + rr * 7;
    if (rbase < 50) {
      const int r = rbase * 2 + half;
      nbu_e[rr] = user_idx_t[ub + r];
      nbi_e[rr] = item_idx_t[ibx + r];
    } else {
      nbu_e[rr] = 0; nbi_e[rr] = 0;
    }
  }
  const int mr = (mrow < KN) ? mrow : 0;
  nbu_m = user_idx_t[ub + mr];
  nbi_m = item_idx_t[ibx + mr];
}

__device__ __forceinline__ void gather_emb(
    const unsigned short* __restrict__ ws, int w, int c,
    const int* nbu_e, const int* nbi_e, unsigned int* evu, unsigned int* evi) {
#pragma unroll
  for (int rr = 0; rr < 8; ++rr) {
    const int rbase = w + rr * 7;
    if (rbase < 50) {
      evu[rr] = *reinterpret_cast<const unsigned int*>(
          ws + EMBU_OFF + (size_t)nbu_e[rr] * 64 + c * 2);
      evi[rr] = *reinterpret_cast<const unsigned int*>(
          ws + EMBI_OFF + (size_t)nbi_e[rr] * 64 + c * 2);
    } else {
      evu[rr] = 0u; evi[rr] = 0u;
    }
  }
}

// Persistent-block version: each block handles ITERS consecutive b, staging
// weights once and software-pipelining idx+emb gathers of b+1 under the MLP
// of b. Two barriers per iteration.
__launch_bounds__(448, 4)
__global__ void cnn_mfma10(
    const unsigned short* __restrict__ ws,
    const float* __restrict__ b1, const float* __restrict__ b2,
    const float* __restrict__ b3, const float* __restrict__ b4,
    const float* __restrict__ w5, const float* __restrict__ b5,
    const int* __restrict__ user_idx_t, const int* __restrict__ item_idx_t,
    const int* __restrict__ user_idxs, const int* __restrict__ item_idxs,
    float* __restrict__ out, int B) {
  __shared__ __align__(16) unsigned short S[S_TOT];
  __shared__ float s_red[7];

  const int tid = threadIdx.x;
  const int w = tid >> 6;
  const int lane = tid & 63;
  const int l15 = lane & 15, quad = lane >> 4;
  const int mrow = w * 16 + l15;
  const int c = lane & 31, half = lane >> 5;

  const int bbase = blockIdx.x * ITERS;
  const int nit = (B - bbase < ITERS) ? (B - bbase) : ITERS;
  if (nit <= 0) return;

  // ---- weight staging + pad zeroing (ONCE per block) ----
  short8 wtmp[4];
#pragma unroll
  for (int i = 0; i < 4; ++i)
    wtmp[i] = reinterpret_cast<const short8*>(ws)[tid + i * 448];
  {
    // pad zeroing: physical bytes of logical positions 100..127 per Et row
    // (byte-disjoint from et_store writes which cover logical 0..99); these
    // zeros survive all iterations.
    const short8 z8 = {0, 0, 0, 0, 0, 0, 0, 0};
    const uint2 z2 = {0u, 0u};
    for (int i = tid; i < 512; i += 448) {
      const int buf = i >> 8;             // 0=u, 1=i
      const int rem = i & 255;
      const int row = rem >> 2, ci = rem & 3;
      const int sw = (row >> 3) & 7;
      const int base = (buf ? ETI_OFF : ETU_OFF) + row * ET_STRIDE;
      if (ci == 0) {
        *reinterpret_cast<uint2*>(&S[base + ((12 ^ sw) << 3) + 4]) = z2;
      } else {
        *reinterpret_cast<short8*>(&S[base + (((12 + ci) ^ sw) << 3)]) = z8;
      }
    }
  }
#pragma unroll
  for (int i = 0; i < 4; ++i)
    reinterpret_cast<short8*>(S)[tid + i * 448] = wtmp[i];

  // ---- prologue: idx + emb gathers for b0 ----
  int nbu_e[8], nbi_e[8], nbu_m, nbi_m;
  unsigned int evu[8], evi[8];
  load_idx(bbase, w, half, mrow, user_idx_t, item_idx_t, user_idxs, item_idxs,
           nbu_e, nbi_e, nbu_m, nbi_m);
  gather_emb(ws, w, c, nbu_e, nbi_e, evu, evi);

  for (int it = 0; it < nit; ++it) {
    const int b = bbase + it;

    // scr gathers for current b (latency hides under et_store + barrier)
    short8 sbu[4], sbi[4];
    {
      const unsigned short* arow = ws + SCRU_OFF + (size_t)nbu_m * 128;
#pragma unroll
      for (int k = 0; k < 4; ++k)
        sbu[k] = *reinterpret_cast<const short8*>(arow + k * 32 + quad * 8);
    }
    {
      const unsigned short* arow = ws + SCRI_OFF + (size_t)nbi_m * 128;
#pragma unroll
      for (int k = 0; k < 4; ++k)
        sbi[k] = *reinterpret_cast<const short8*>(arow + k * 32 + quad * 8);
    }

    // Et staging for both sources (safe: B2 of previous iter fenced reads)
    et_store(S, evu, w, c, half, ETU_OFF);
    et_store(S, evi, w, c, half, ETI_OFF);
    __syncthreads();  // B1: Et(b) visible (it==0: also weights/zeros)

    short8 x0, x1, x2, x3;
    pool_mfma(S + ETU_OFF, sbu, l15, quad, x0, x1);
    pool_mfma(S + ETI_OFF, sbi, l15, quad, x2, x3);

    // ---- prefetch b+1 (idx chain + emb gathers) under the MLP ----
    if (it + 1 < nit) {
      load_idx(b + 1, w, half, mrow, user_idx_t, item_idx_t, user_idxs,
               item_idxs, nbu_e, nbi_e, nbu_m, nbi_m);
      gather_emb(ws, w, c, nbu_e, nbi_e, evu, evi);
    }

    // ---- MLP fully in registers; W1..W3 from LDS, W4 from global ----
    // L1: 128 -> 64
    f32x4 y[4];
#pragma unroll
    for (int po = 0; po < 4; ++po) y[po] = (f32x4){0.f, 0.f, 0.f, 0.f};
    {
      short8 xf[4] = {x0, x1, x2, x3};
#pragma unroll
      for (int k4 = 0; k4 < 4; ++k4)
#pragma unroll
        for (int po = 0; po < 4; ++po) {
          short8 wa = *reinterpret_cast<const short8*>(
              S + W1_OFF + ((po * 4 + k4) * 64 + lane) * 8);
          y[po] = __builtin_amdgcn_mfma_f32_16x16x32_bf16(wa, xf[k4], y[po], 0, 0, 0);
        }
    }
#pragma unroll
    for (int po = 0; po < 4; ++po) {
      const float4 bb = *reinterpret_cast<const float4*>(b1 + po * 16 + quad * 4);
#pragma unroll
      for (int r = 0; r < 4; ++r) y[po][r] = fmaxf(y[po][r] + bb[r], 0.f);
    }
    short8 g0 = pk2(y[0], y[1]), g1 = pk2(y[2], y[3]);

    // L2: 64 -> 64
    f32x4 v[4];
#pragma unroll
    for (int po = 0; po < 4; ++po) v[po] = (f32x4){0.f, 0.f, 0.f, 0.f};
#pragma unroll
    for (int k4 = 0; k4 < 2; ++k4) {
      short8 gf = k4 ? g1 : g0;
#pragma unroll
      for (int po = 0; po < 4; ++po) {
        short8 wa = *reinterpret_cast<const short8*>(
            S + W2_OFF + ((po * 2 + k4) * 64 + lane) * 8);
        v[po] = __builtin_amdgcn_mfma_f32_16x16x32_bf16(wa, gf, v[po], 0, 0, 0);
      }
    }
#pragma unroll
    for (int po = 0; po < 4; ++po) {
      const float4 bb = *reinterpret_cast<const float4*>(b2 + po * 16 + quad * 4);
#pragma unroll
      for (int r = 0; r < 4; ++r) v[po][r] = fmaxf(v[po][r] + bb[r], 0.f);
    }
    short8 h0 = pk2(v[0], v[1]), h1 = pk2(v[2], v[3]);

    // L3: 64 -> 32
    f32x4 t3[2];
    t3[0] = (f32x4){0.f, 0.f, 0.f, 0.f};
    t3[1] = (f32x4){0.f, 0.f, 0.f, 0.f};
#pragma unroll
    for (int k4 = 0; k4 < 2; ++k4) {
      short8 gf = k4 ? h1 : h0;
#pragma unroll
      for (int po = 0; po < 2; ++po) {
        short8 wa = *reinterpret_cast<const short8*>(
            S + W3_OFF + ((po * 2 + k4) * 64 + lane) * 8);
        t3[po] = __builtin_amdgcn_mfma_f32_16x16x32_bf16(wa, gf, t3[po], 0, 0, 0);
      }
    }
#pragma unroll
    for (int po = 0; po < 2; ++po) {
      const float4 bb = *reinterpret_cast<const float4*>(b3 + po * 16 + quad * 4);
#pragma unroll
      for (int r = 0; r < 4; ++r) t3[po][r] = fmaxf(t3[po][r] + bb[r], 0.f);
    }
    short8 q0 = pk2(t3[0], t3[1]);

    // L4: 32 -> 32 (weights from GLOBAL), fused with L5 + sigmoid + mean
    f32x4 u[2];
    u[0] = (f32x4){0.f, 0.f, 0.f, 0.f};
    u[1] = (f32x4){0.f, 0.f, 0.f, 0.f};
#pragma unroll
    for (int po = 0; po < 2; ++po) {
      short8 wa = *reinterpret_cast<const short8*>(ws + W4_OFF + (po * 64 + lane) * 8);
      u[po] = __builtin_amdgcn_mfma_f32_16x16x32_bf16(wa, q0, u[po], 0, 0, 0);
    }
    float part = 0.f;
#pragma unroll
    for (int po = 0; po < 2; ++po) {
      const float4 bb = *reinterpret_cast<const float4*>(b4 + po * 16 + quad * 4);
      const float4 wv = *reinterpret_cast<const float4*>(w5 + po * 16 + quad * 4);
#pragma unroll
      for (int r = 0; r < 4; ++r)
        part = fmaf(fmaxf(u[po][r] + bb[r], 0.f), wv[r], part);
    }
    part += __shfl_xor(part, 16, 64);
    part += __shfl_xor(part, 32, 64);
    float sig = 1.f / (1.f + expf(-(part + b5[0])));
    if (mrow >= KN) sig = 0.f;
    sig += __shfl_xor(sig, 1, 64);
    sig += __shfl_xor(sig, 2, 64);
    sig += __shfl_xor(sig, 4, 64);
    sig += __shfl_xor(sig, 8, 64);
    if (lane == 0) s_red[w] = sig;
    __syncthreads();  // B2: s_red ready AND all Et(b) reads complete
    if (tid == 0) {
      float acc = 0.f;
#pragma unroll
      for (int i = 0; i < 7; ++i) acc += s_red[i];
      out[b] = acc * (1.0f / KN);
    }
    // s_red(b) is only re-written after the NEXT B1 + pools + MLP, so the
    // tid0 read above is race-free even as other waves enter iteration b+1.
  }
}

extern "C" void kernel_launch(void* const* d_in, const int* in_sizes, int n_in,
                              void* d_out, int out_size, void* d_ws,
                              size_t ws_size, hipStream_t stream) {
  const float* user_emb = (const float*)d_in[0];
  const float* item_emb = (const float*)d_in[1];
  const float* user_scr = (const float*)d_in[2];
  const float* item_scr = (const float*)d_in[3];
  const float* w1 = (const float*)d_in[4];
  const float* b1 = (const float*)d_in[5];
  const float* w2 = (const float*)d_in[6];
  const float* b2 = (const float*)d_in[7];
  const float* w3 = (const float*)d_in[8];
  const float* b3 = (const float*)d_in[9];
  const float* w4 = (const float*)d_in[10];
  const float* b4 = (const float*)d_in[11];
  const float* w5 = (const float*)d_in[12];
  const float* b5 = (const float*)d_in[13];
  const int* user_idx_t = (const int*)d_in[14];
  const int* item_idx_t = (const int*)d_in[15];
  const int* user_idxs = (const int*)d_in[16];
  const int* item_idxs = (const int*)d_in[17];
  unsigned short* wsw = (unsigned short*)d_ws;

  prep<<<dim3(2048), dim3(256), 0, stream>>>(
      w1, w2, w3, w4, user_scr, item_scr, user_emb, item_emb, wsw);

  const int B = in_sizes[16];  // 8192
  const int nblk = (B + ITERS - 1) / ITERS;  // 512 -> exactly 2 blocks/CU
  cnn_mfma10<<<dim3(nblk), dim3(448), 0, stream>>>(
      wsw, b1, b2, b3, b4, w5, b5, user_idx_t, item_idx_t, user_idxs,
      item_idxs, (float*)d_out, B);
}

// Round 9
// 386.824 us; speedup vs baseline: 2.1715x; 2.1715x over previous
//
#include <hip/hip_runtime.h>
#include <hip/hip_bf16.h>
#include <math.h>

typedef __attribute__((ext_vector_type(8))) short short8;
typedef __attribute__((ext_vector_type(4))) float f32x4;

#define KN 100

// ---- ws layout (halfword units) ----
// Weights stored as A-fragments with k-slot permutation sigma(quad,s):
//   element index i = 32*k4 + 16*(s>>2) + 4*quad + (s&3)
// scr rows stored column-PERMUTED with matching P(): position
//   p = 32*k4 + 8*quad + s  holds element j = 32*k4 + 16*(s>>2) + 4*quad + (s&3)
// P maps {0..99} onto {0..99} and {100..127} onto {100..127}: per Et row the
// staged bytes are exactly hw 0..99 and pad is exactly hw 100..127.
#define W1_OFF 0         // 64x128 bf16, kt=4
#define W2_OFF 8192      // 64x64,  kt=2
#define W3_OFF 12288     // 32x64,  kt=2
#define W4_OFF 14336     // 32x32,  kt=1  (stays in GLOBAL; not staged to LDS)
#define SCRU_OFF 16384                        // 100000 x 128 bf16 (P-permuted, zero-pad j>=100)
#define SCRI_OFF (SCRU_OFF + 100000 * 128)    // 50000 x 128
#define EMBU_OFF (SCRI_OFF + 50000 * 128)     // 100000 x 64 bf16
#define EMBI_OFF (EMBU_OFF + 100000 * 64)     // 50000 x 64

// ---- LDS (halfword offsets): [W1..W3 14336][ETU 8704][ETI 8704]
// = 31744 hw = 63488 B -> 2 blocks/CU. Row stride 136 hw; chunk swizzle:
// hw offset p ^= ((row>>3)&7)<<3 on both store and read.
#define ET_STRIDE 136
#define ETU_OFF 14336
#define ETI_OFF (14336 + 64 * ET_STRIDE)
#define S_TOT   (14336 + 2 * 64 * ET_STRIDE)   // 31744 hw

__device__ __forceinline__ unsigned short f2bf(float f) {
  __hip_bfloat16 h = __float2bfloat16(f);
  return __builtin_bit_cast(unsigned short, h);
}

__device__ __forceinline__ void st8(unsigned short* d, float4 a, float4 b) {
  short8 h;
  h[0] = (short)f2bf(a.x); h[1] = (short)f2bf(a.y);
  h[2] = (short)f2bf(a.z); h[3] = (short)f2bf(a.w);
  h[4] = (short)f2bf(b.x); h[5] = (short)f2bf(b.y);
  h[6] = (short)f2bf(b.z); h[7] = (short)f2bf(b.w);
  *reinterpret_cast<short8*>(d) = h;
}

__device__ __forceinline__ short8 pk2(f32x4 a, f32x4 b) {
  short8 h;
  h[0] = (short)f2bf(a[0]); h[1] = (short)f2bf(a[1]);
  h[2] = (short)f2bf(a[2]); h[3] = (short)f2bf(a[3]);
  h[4] = (short)f2bf(b[0]); h[5] = (short)f2bf(b[1]);
  h[6] = (short)f2bf(b[2]); h[7] = (short)f2bf(b[3]);
  return h;
}

// Streaming prep (grid-stride): unchanged (verified r4-r8).
#define PREP_UNITS (15360 + 2400000 + 1200000)
__global__ void prep(const float* __restrict__ w1, const float* __restrict__ w2,
                     const float* __restrict__ w3, const float* __restrict__ w4,
                     const float* __restrict__ uscr, const float* __restrict__ iscr,
                     const float* __restrict__ uemb, const float* __restrict__ iemb,
                     unsigned short* __restrict__ ws) {
  const float4 z4 = {0.f, 0.f, 0.f, 0.f};
  const int stride = gridDim.x * 256;
  for (int t = blockIdx.x * 256 + threadIdx.x; t < PREP_UNITS; t += stride) {
    if (t < 15360) {
      const float* src; int rel, o, i, kt, base;
      if (t < 8192)       { src = w1; rel = t;         o = rel >> 7; i = rel & 127; kt = 4; base = W1_OFF; }
      else if (t < 12288) { src = w2; rel = t - 8192;  o = rel >> 6; i = rel & 63;  kt = 2; base = W2_OFF; }
      else if (t < 14336) { src = w3; rel = t - 12288; o = rel >> 6; i = rel & 63;  kt = 2; base = W3_OFF; }
      else                { src = w4; rel = t - 14336; o = rel >> 5; i = rel & 31;  kt = 1; base = W4_OFF; }
      int n = o >> 4, l15 = o & 15, k = i >> 5;
      int quad = (i >> 2) & 3, s = ((i >> 4) & 1) * 4 + (i & 3);
      ws[base + ((n * kt + k) * 64 + quad * 16 + l15) * 8 + s] = f2bf(src[rel]);
      continue;
    }
    int rel = t - 15360;
    if (rel < 2400000) {  // scr: 16 threads/row, 8 outputs each (P-permuted)
      const float* src; unsigned short* dst; int row, g;
      if (rel < 1600000) {
        row = rel >> 4; g = rel & 15;
        src = uscr + (size_t)row * 100;
        dst = ws + SCRU_OFF + (size_t)row * 128 + g * 8;
      } else {
        int q = rel - 1600000; row = q >> 4; g = q & 15;
        src = iscr + (size_t)row * 100;
        dst = ws + SCRI_OFF + (size_t)row * 128 + g * 8;
      }
      const int jb = 32 * (g >> 2) + 4 * (g & 3);
      float4 va = (jb <= 96) ? *reinterpret_cast<const float4*>(src + jb) : z4;
      float4 vb = (jb <= 80) ? *reinterpret_cast<const float4*>(src + jb + 16) : z4;
      st8(dst, va, vb);
      continue;
    }
    rel -= 2400000;
    {  // emb: 8 threads/row, 8 outputs each (64 cols)
      const float* src; unsigned short* dst; int row, g;
      if (rel < 800000) {
        row = rel >> 3; g = rel & 7;
        src = uemb + (size_t)row * 64;
        dst = ws + EMBU_OFF + (size_t)row * 64 + g * 8;
      } else {
        int q = rel - 800000; row = q >> 3; g = q & 7;
        src = iemb + (size_t)row * 64;
        dst = ws + EMBI_OFF + (size_t)row * 64 + g * 8;
      }
      float4 va = *reinterpret_cast<const float4*>(src + g * 8);
      float4 vb = *reinterpret_cast<const float4*>(src + g * 8 + 4);
      st8(dst, va, vb);
    }
  }
}

// Pool MFMA for one source: acc = X^T tiles (lane = m, regs = feature rows).
__device__ __forceinline__ void pool_mfma(const unsigned short* __restrict__ Sb,
                                          const short8* sb, int l15, int quad,
                                          short8& f0, short8& f1) {
  f32x4 acc[4];
#pragma unroll
  for (int po = 0; po < 4; ++po) acc[po] = (f32x4){0.f, 0.f, 0.f, 0.f};
#pragma unroll
  for (int k4 = 0; k4 < 4; ++k4) {
#pragma unroll
    for (int po = 0; po < 4; ++po) {
      const int row = po * 16 + l15;
      const int hw = row * ET_STRIDE + (((k4 * 4 + quad) ^ ((row >> 3) & 7)) << 3);
      short8 ea = *reinterpret_cast<const short8*>(Sb + hw);
      acc[po] = __builtin_amdgcn_mfma_f32_16x16x32_bf16(ea, sb[k4], acc[po], 0, 0, 0);
    }
  }
  f0 = pk2(acc[0], acc[1]);
  f1 = pk2(acc[2], acc[3]);
}

// Et staging from pre-gathered registers (u32-paired via shfl_xor across
// halves, chunk-swizzled addresses). Wave w writes j-pairs rbase=sbase..
// sbase+scnt-1 (contiguous per-wave partition of 0..49). Only logical
// hw 0..99 per row is written.
__device__ __forceinline__ void et_store(unsigned short* __restrict__ S,
                                         const unsigned int* ev, int sbase,
                                         int scnt, int c, int half, int base) {
#pragma unroll
  for (int rr = 0; rr < 8; ++rr) {
    if (rr < scnt) {
      const int r0 = (sbase + rr) * 2;
      const int p0 = ((r0 >> 5) << 5) | (((r0 >> 2) & 3) << 3) |
                     (((r0 >> 4) & 1) << 2) | (r0 & 3);  // even
      const int sw = ((c >> 2) & 7) << 3;  // = ((row>>3)&7)<<3 for both halves
      const int q = (2 * c + half) * ET_STRIDE + (p0 ^ sw);  // even hw offset
      unsigned int v = ev[rr];
      unsigned int p = __shfl_xor(v, 32, 64);
      unsigned int d = half ? ((v & 0xffff0000u) | (p >> 16))
                            : ((v & 0x0000ffffu) | (p << 16));
      *reinterpret_cast<unsigned int*>(&S[base + q]) = d;
    }
  }
}

__launch_bounds__(448, 4)
__global__ void cnn_mfma11(
    const unsigned short* __restrict__ ws,
    const float* __restrict__ b1, const float* __restrict__ b2,
    const float* __restrict__ b3, const float* __restrict__ b4,
    const float* __restrict__ w5, const float* __restrict__ b5,
    const int* __restrict__ user_idx_t, const int* __restrict__ item_idx_t,
    const int* __restrict__ user_idxs, const int* __restrict__ item_idxs,
    float* __restrict__ out) {
  __shared__ __align__(16) unsigned short S[S_TOT];
  __shared__ float s_red[7];

  const int b = blockIdx.x;
  const int tid = threadIdx.x;
  const int w = tid >> 6;
  const int lane = tid & 63;
  const int l15 = lane & 15, quad = lane >> 4;
  const int mrow = w * 16 + l15;
  const int c = lane & 31, half = lane >> 5;

  // wave w's contiguous staging range: rbase in [sbase, sbase+scnt)
  const int sbase = (50 * w) / 7;
  const int scnt = (50 * (w + 1)) / 7 - sbase;  // 7,7,7,7,7,7,8

  // ---- issue W1..W3 copy loads first (1792 chunks = 448 x 4, exact) ----
  short8 wtmp[4];
#pragma unroll
  for (int i = 0; i < 4; ++i)
    wtmp[i] = reinterpret_cast<const short8*>(ws)[tid + i * 448];

  // ---- per-wave coalesced idx self-service (no LDS, no barrier):
  // lane group 0: user staging idx[2*sbase + g], g<2*scnt
  // lane group 1: user mrow idx[w*16 + g]  (clamped <100)
  // lane group 2: item staging          group 3: item mrow
  const int ub = user_idxs[b] * KN;
  const int ibx = item_idxs[b] * KN;
  int myidx;
  {
    const int g = lane & 15;
    const int grp = lane >> 4;
    const int mr = (w * 16 + g < KN) ? (w * 16 + g) : 0;
    const int sg = (g < 2 * scnt) ? (2 * sbase + g) : 0;
    const int off = (grp & 1) ? mr : sg;
    const int bse = (grp & 2) ? ibx : ub;
    const int* tbl = (grp & 2) ? item_idx_t : user_idx_t;
    myidx = tbl[bse + off];
  }
  const int nbu_m = __shfl(myidx, 16 + l15, 64);
  const int nbi_m = __shfl(myidx, 48 + l15, 64);

  // ---- emb gathers for both sources (rows from shfl'd staging idx) ----
  unsigned int evu[8], evi[8];
#pragma unroll
  for (int rr = 0; rr < 8; ++rr) {
    if (rr < scnt) {
      const int src = 2 * rr + half;  // source lane within each staging group
      const int nu = __shfl(myidx, src, 64);
      const int ni = __shfl(myidx, 32 + src, 64);
      evu[rr] = *reinterpret_cast<const unsigned int*>(
          ws + EMBU_OFF + (size_t)nu * 64 + c * 2);
      evi[rr] = *reinterpret_cast<const unsigned int*>(
          ws + EMBI_OFF + (size_t)ni * 64 + c * 2);
    } else {
      evu[rr] = 0u; evi[rr] = 0u;
    }
  }
  // scr frag gathers (current lane's m-row)
  short8 sbu[4], sbi[4];
  {
    const unsigned short* arow = ws + SCRU_OFF + (size_t)nbu_m * 128;
#pragma unroll
    for (int k = 0; k < 4; ++k)
      sbu[k] = *reinterpret_cast<const short8*>(arow + k * 32 + quad * 8);
  }
  {
    const unsigned short* arow = ws + SCRI_OFF + (size_t)nbi_m * 128;
#pragma unroll
    for (int k = 0; k < 4; ++k)
      sbi[k] = *reinterpret_cast<const short8*>(arow + k * 32 + quad * 8);
  }

  // ---- pad zeroing: ONLY genuinely-pad bytes (logical hw 100..127 per row),
  // byte-disjoint from et_store writes (logical 0..99) -> safe unordered in
  // the same phase (verified r7). Per row/buf: 8B tail of chunk 12 + 13..15.
  {
    const short8 z8 = {0, 0, 0, 0, 0, 0, 0, 0};
    const uint2 z2 = {0u, 0u};
    for (int i = tid; i < 512; i += 448) {
      const int buf = i >> 8;             // 0=u, 1=i
      const int rem = i & 255;
      const int row = rem >> 2, ci = rem & 3;
      const int sw = (row >> 3) & 7;
      const int base = (buf ? ETI_OFF : ETU_OFF) + row * ET_STRIDE;
      if (ci == 0) {
        *reinterpret_cast<uint2*>(&S[base + ((12 ^ sw) << 3) + 4]) = z2;
      } else {
        *reinterpret_cast<short8*>(&S[base + (((12 + ci) ^ sw) << 3)]) = z8;
      }
    }
  }

  // ---- weight stores + Et staging for both sources, then ONE barrier ----
#pragma unroll
  for (int i = 0; i < 4; ++i)
    reinterpret_cast<short8*>(S)[tid + i * 448] = wtmp[i];
  et_store(S, evu, sbase, scnt, c, half, ETU_OFF);
  et_store(S, evi, sbase, scnt, c, half, ETI_OFF);
  __syncthreads();

  // ---- both pools back-to-back (no further barriers until the reduce) ----
  short8 x0, x1, x2, x3;
  pool_mfma(S + ETU_OFF, sbu, l15, quad, x0, x1);
  pool_mfma(S + ETI_OFF, sbi, l15, quad, x2, x3);

  // ---- MLP fully in registers; W1..W3 from LDS, W4 from global ----
  // L1: 128 -> 64
  f32x4 y[4];
#pragma unroll
  for (int po = 0; po < 4; ++po) y[po] = (f32x4){0.f, 0.f, 0.f, 0.f};
  {
    short8 xf[4] = {x0, x1, x2, x3};
#pragma unroll
    for (int k4 = 0; k4 < 4; ++k4)
#pragma unroll
      for (int po = 0; po < 4; ++po) {
        short8 wa = *reinterpret_cast<const short8*>(
            S + W1_OFF + ((po * 4 + k4) * 64 + lane) * 8);
        y[po] = __builtin_amdgcn_mfma_f32_16x16x32_bf16(wa, xf[k4], y[po], 0, 0, 0);
      }
  }
#pragma unroll
  for (int po = 0; po < 4; ++po) {
    const float4 bb = *reinterpret_cast<const float4*>(b1 + po * 16 + quad * 4);
#pragma unroll
    for (int r = 0; r < 4; ++r) y[po][r] = fmaxf(y[po][r] + bb[r], 0.f);
  }
  short8 g0 = pk2(y[0], y[1]), g1 = pk2(y[2], y[3]);

  // L2: 64 -> 64
  f32x4 v[4];
#pragma unroll
  for (int po = 0; po < 4; ++po) v[po] = (f32x4){0.f, 0.f, 0.f, 0.f};
#pragma unroll
  for (int k4 = 0; k4 < 2; ++k4) {
    short8 gf = k4 ? g1 : g0;
#pragma unroll
    for (int po = 0; po < 4; ++po) {
      short8 wa = *reinterpret_cast<const short8*>(
          S + W2_OFF + ((po * 2 + k4) * 64 + lane) * 8);
      v[po] = __builtin_amdgcn_mfma_f32_16x16x32_bf16(wa, gf, v[po], 0, 0, 0);
    }
  }
#pragma unroll
  for (int po = 0; po < 4; ++po) {
    const float4 bb = *reinterpret_cast<const float4*>(b2 + po * 16 + quad * 4);
#pragma unroll
    for (int r = 0; r < 4; ++r) v[po][r] = fmaxf(v[po][r] + bb[r], 0.f);
  }
  short8 h0 = pk2(v[0], v[1]), h1 = pk2(v[2], v[3]);

  // L3: 64 -> 32
  f32x4 t3[2];
  t3[0] = (f32x4){0.f, 0.f, 0.f, 0.f};
  t3[1] = (f32x4){0.f, 0.f, 0.f, 0.f};
#pragma unroll
  for (int k4 = 0; k4 < 2; ++k4) {
    short8 gf = k4 ? h1 : h0;
#pragma unroll
    for (int po = 0; po < 2; ++po) {
      short8 wa = *reinterpret_cast<const short8*>(
          S + W3_OFF + ((po * 2 + k4) * 64 + lane) * 8);
      t3[po] = __builtin_amdgcn_mfma_f32_16x16x32_bf16(wa, gf, t3[po], 0, 0, 0);
    }
  }
#pragma unroll
  for (int po = 0; po < 2; ++po) {
    const float4 bb = *reinterpret_cast<const float4*>(b3 + po * 16 + quad * 4);
#pragma unroll
    for (int r = 0; r < 4; ++r) t3[po][r] = fmaxf(t3[po][r] + bb[r], 0.f);
  }
  short8 q0 = pk2(t3[0], t3[1]);

  // L4: 32 -> 32 (weights from GLOBAL), fused with L5 + sigmoid + mean
  f32x4 u[2];
  u[0] = (f32x4){0.f, 0.f, 0.f, 0.f};
  u[1] = (f32x4){0.f, 0.f, 0.f, 0.f};
#pragma unroll
  for (int po = 0; po < 2; ++po) {
    short8 wa = *reinterpret_cast<const short8*>(ws + W4_OFF + (po * 64 + lane) * 8);
    u[po] = __builtin_amdgcn_mfma_f32_16x16x32_bf16(wa, q0, u[po], 0, 0, 0);
  }
  float part = 0.f;
#pragma unroll
  for (int po = 0; po < 2; ++po) {
    const float4 bb = *reinterpret_cast<const float4*>(b4 + po * 16 + quad * 4);
    const float4 wv = *reinterpret_cast<const float4*>(w5 + po * 16 + quad * 4);
#pragma unroll
    for (int r = 0; r < 4; ++r)
      part = fmaf(fmaxf(u[po][r] + bb[r], 0.f), wv[r], part);
  }
  // sum the 4 quad-partials for this m (lanes l15, l15+16, l15+32, l15+48)
  part += __shfl_xor(part, 16, 64);
  part += __shfl_xor(part, 32, 64);
  float sig = 1.f / (1.f + expf(-(part + b5[0])));
  if (mrow >= KN) sig = 0.f;
  // sum over the wave's 16 rows (each quad-group holds identical copies)
  sig += __shfl_xor(sig, 1, 64);
  sig += __shfl_xor(sig, 2, 64);
  sig += __shfl_xor(sig, 4, 64);
  sig += __shfl_xor(sig, 8, 64);
  if (lane == 0) s_red[w] = sig;
  __syncthreads();
  if (tid == 0) {
    float acc = 0.f;
#pragma unroll
    for (int i = 0; i < 7; ++i) acc += s_red[i];
    out[b] = acc * (1.0f / KN);
  }
}

extern "C" void kernel_launch(void* const* d_in, const int* in_sizes, int n_in,
                              void* d_out, int out_size, void* d_ws,
                              size_t ws_size, hipStream_t stream) {
  const float* user_emb = (const float*)d_in[0];
  const float* item_emb = (const float*)d_in[1];
  const float* user_scr = (const float*)d_in[2];
  const float* item_scr = (const float*)d_in[3];
  const float* w1 = (const float*)d_in[4];
  const float* b1 = (const float*)d_in[5];
  const float* w2 = (const float*)d_in[6];
  const float* b2 = (const float*)d_in[7];
  const float* w3 = (const float*)d_in[8];
  const float* b3 = (const float*)d_in[9];
  const float* w4 = (const float*)d_in[10];
  const float* b4 = (const float*)d_in[11];
  const float* w5 = (const float*)d_in[12];
  const float* b5 = (const float*)d_in[13];
  const int* user_idx_t = (const int*)d_in[14];
  const int* item_idx_t = (const int*)d_in[15];
  const int* user_idxs = (const int*)d_in[16];
  const int* item_idxs = (const int*)d_in[17];
  unsigned short* wsw = (unsigned short*)d_ws;

  prep<<<dim3(2048), dim3(256), 0, stream>>>(
      w1, w2, w3, w4, user_scr, item_scr, user_emb, item_emb, wsw);

  const int B = in_sizes[16];  // 8192
  cnn_mfma11<<<dim3(B), dim3(448), 0, stream>>>(
      wsw, b1, b2, b3, b4, w5, b5, user_idx_t, item_idx_t, user_idxs,
      item_idxs, (float*)d_out);
}

// Round 10
// 339.255 us; speedup vs baseline: 2.4759x; 1.1402x over previous
//
#include <hip/hip_runtime.h>
#include <hip/hip_bf16.h>
#include <math.h>

typedef __attribute__((ext_vector_type(8))) short short8;
typedef __attribute__((ext_vector_type(4))) float f32x4;

#define KN 100

// ---- ws layout (halfword units) ----
// Weights stored as A-fragments with k-slot permutation sigma(quad,s):
//   element index i = 32*k4 + 16*(s>>2) + 4*quad + (s&3)
// scr rows stored column-PERMUTED with matching P(): position
//   p = 32*k4 + 8*quad + s  holds element j = 32*k4 + 16*(s>>2) + 4*quad + (s&3)
#define W1_OFF 0         // 64x128 bf16, kt=4
#define W2_OFF 8192      // 64x64,  kt=2
#define W3_OFF 12288     // 32x64,  kt=2
#define W4_OFF 14336     // 32x32,  kt=1  (stays in GLOBAL; not staged to LDS)
#define SCRU_OFF 16384                        // 100000 x 128 bf16 (P-permuted, zero-pad j>=100)
#define SCRI_OFF (SCRU_OFF + 100000 * 128)    // 50000 x 128
#define EMBU_OFF (SCRI_OFF + 50000 * 128)     // 100000 x 64 bf16
#define EMBI_OFF (EMBU_OFF + 100000 * 64)     // 50000 x 64

// ---- LDS (halfword offsets): [W1..W3 14336][ETU 8704][ETI 8704]
// = 31744 hw = 63488 B (+ s_nb/s_red statics = 64412 B <= 65536 limit).
// Et row stride 136 hw; chunk swizzle: hw offset p ^= ((row>>3)&7)<<3 on both
// store and read. Only chunks 12..15 (^sw) can hold unwritten pad positions.
#define ET_STRIDE 136
#define ETU_OFF 14336
#define ETI_OFF (14336 + 64 * ET_STRIDE)
#define S_TOT   (14336 + 2 * 64 * ET_STRIDE)   // 31744 hw

__device__ __forceinline__ unsigned short f2bf(float f) {
  __hip_bfloat16 h = __float2bfloat16(f);
  return __builtin_bit_cast(unsigned short, h);
}

__device__ __forceinline__ void st8(unsigned short* d, float4 a, float4 b) {
  short8 h;
  h[0] = (short)f2bf(a.x); h[1] = (short)f2bf(a.y);
  h[2] = (short)f2bf(a.z); h[3] = (short)f2bf(a.w);
  h[4] = (short)f2bf(b.x); h[5] = (short)f2bf(b.y);
  h[6] = (short)f2bf(b.z); h[7] = (short)f2bf(b.w);
  *reinterpret_cast<short8*>(d) = h;
}

__device__ __forceinline__ short8 pk2(f32x4 a, f32x4 b) {
  short8 h;
  h[0] = (short)f2bf(a[0]); h[1] = (short)f2bf(a[1]);
  h[2] = (short)f2bf(a[2]); h[3] = (short)f2bf(a[3]);
  h[4] = (short)f2bf(b[0]); h[5] = (short)f2bf(b[1]);
  h[6] = (short)f2bf(b[2]); h[7] = (short)f2bf(b[3]);
  return h;
}

// Streaming prep: weights (A-frag sigma layout) + scr (bf16, P-permuted cols,
// pad to 128) + emb (bf16 row-major). Exact r4 form (best measured).
__global__ void prep(const float* __restrict__ w1, const float* __restrict__ w2,
                     const float* __restrict__ w3, const float* __restrict__ w4,
                     const float* __restrict__ uscr, const float* __restrict__ iscr,
                     const float* __restrict__ uemb, const float* __restrict__ iemb,
                     unsigned short* __restrict__ ws) {
  int t = blockIdx.x * 256 + threadIdx.x;
  if (t < 15360) {
    const float* src; int rel, o, i, kt, base;
    if (t < 8192)       { src = w1; rel = t;         o = rel >> 7; i = rel & 127; kt = 4; base = W1_OFF; }
    else if (t < 12288) { src = w2; rel = t - 8192;  o = rel >> 6; i = rel & 63;  kt = 2; base = W2_OFF; }
    else if (t < 14336) { src = w3; rel = t - 12288; o = rel >> 6; i = rel & 63;  kt = 2; base = W3_OFF; }
    else                { src = w4; rel = t - 14336; o = rel >> 5; i = rel & 31;  kt = 1; base = W4_OFF; }
    int n = o >> 4, l15 = o & 15, k = i >> 5;
    int quad = (i >> 2) & 3, s = ((i >> 4) & 1) * 4 + (i & 3);
    ws[base + ((n * kt + k) * 64 + quad * 16 + l15) * 8 + s] = f2bf(src[rel]);
    return;
  }
  int rel = t - 15360;
  const float4 z4 = {0.f, 0.f, 0.f, 0.f};
  if (rel < 2400000) {  // scr: 16 threads/row, 8 outputs each (P-permuted)
    const float* src; unsigned short* dst; int row, g;
    if (rel < 1600000) {
      row = rel >> 4; g = rel & 15;
      src = uscr + (size_t)row * 100;
      dst = ws + SCRU_OFF + (size_t)row * 128 + g * 8;
    } else {
      int q = rel - 1600000; row = q >> 4; g = q & 15;
      src = iscr + (size_t)row * 100;
      dst = ws + SCRI_OFF + (size_t)row * 128 + g * 8;
    }
    const int jb = 32 * (g >> 2) + 4 * (g & 3);
    float4 va = (jb <= 96) ? *reinterpret_cast<const float4*>(src + jb) : z4;
    float4 vb = (jb <= 80) ? *reinterpret_cast<const float4*>(src + jb + 16) : z4;
    st8(dst, va, vb);
    return;
  }
  rel -= 2400000;
  if (rel < 1200000) {  // emb: 8 threads/row, 8 outputs each (64 cols)
    const float* src; unsigned short* dst; int row, g;
    if (rel < 800000) {
      row = rel >> 3; g = rel & 7;
      src = uemb + (size_t)row * 64;
      dst = ws + EMBU_OFF + (size_t)row * 64 + g * 8;
    } else {
      int q = rel - 800000; row = q >> 3; g = q & 7;
      src = iemb + (size_t)row * 64;
      dst = ws + EMBI_OFF + (size_t)row * 64 + g * 8;
    }
    float4 va = *reinterpret_cast<const float4*>(src + g * 8);
    float4 vb = *reinterpret_cast<const float4*>(src + g * 8 + 4);
    st8(dst, va, vb);
  }
}

// Pool MFMA for one source: acc = X^T tiles (lane = m, regs = feature rows).
// Reads the chunk-swizzled Et buffer; sb = prefetched scr B-frags.
__device__ __forceinline__ void pool_mfma(const unsigned short* __restrict__ Sb,
                                          const short8* sb, int l15, int quad,
                                          short8& f0, short8& f1) {
  f32x4 acc[4];
#pragma unroll
  for (int po = 0; po < 4; ++po) acc[po] = (f32x4){0.f, 0.f, 0.f, 0.f};
#pragma unroll
  for (int k4 = 0; k4 < 4; ++k4) {
#pragma unroll
    for (int po = 0; po < 4; ++po) {
      const int row = po * 16 + l15;
      const int hw = row * ET_STRIDE + (((k4 * 4 + quad) ^ ((row >> 3) & 7)) << 3);
      short8 ea = *reinterpret_cast<const short8*>(Sb + hw);
      acc[po] = __builtin_amdgcn_mfma_f32_16x16x32_bf16(ea, sb[k4], acc[po], 0, 0, 0);
    }
  }
  f0 = pk2(acc[0], acc[1]);
  f1 = pk2(acc[2], acc[3]);
}

__launch_bounds__(448, 4)
__global__ void cnn_mfma7(
    const unsigned short* __restrict__ ws,
    const float* __restrict__ b1, const float* __restrict__ b2,
    const float* __restrict__ b3, const float* __restrict__ b4,
    const float* __restrict__ w5, const float* __restrict__ b5,
    const int* __restrict__ user_idx_t, const int* __restrict__ item_idx_t,
    const int* __restrict__ user_idxs, const int* __restrict__ item_idxs,
    float* __restrict__ out) {
  __shared__ __align__(16) unsigned short S[S_TOT];
  __shared__ int s_nb[2][112];
  __shared__ float s_red[7];

  const int b = blockIdx.x;
  const int tid = threadIdx.x;
  const int w = tid >> 6;
  const int lane = tid & 63;
  const int l15 = lane & 15, quad = lane >> 4;

  // ---- P0: issue W1..W3 copy loads early (latency hides under idx/nb chain)
  // 1792 chunks = 448 threads x 4, exact.
  short8 wtmp[4];
#pragma unroll
  for (int i = 0; i < 4; ++i)
    wtmp[i] = reinterpret_cast<const short8*>(ws)[tid + i * 448];

  // neighbor lists (pad -> 0)
  if (tid < 112) {
    s_nb[0][tid] = (tid < KN) ? user_idx_t[(size_t)user_idxs[b] * KN + tid] : 0;
  } else if (tid >= 128 && tid < 240) {
    int i = tid - 128;
    s_nb[1][i] = (i < KN) ? item_idx_t[(size_t)item_idxs[b] * KN + i] : 0;
  }

  // pad-only zeroing: chunks 12..15 (^sw) of each Et row are the only ones
  // that can hold unwritten (j>=100) positions; chunks 0..11 are fully
  // overwritten by staging. 512 zero-stores total.
  {
    const short8 z8 = {0, 0, 0, 0, 0, 0, 0, 0};
    for (int i = tid; i < 512; i += 448) {
      const int buf = i >> 8;             // 0=u, 1=i
      const int rem = i & 255;
      const int row = rem >> 2, ci = rem & 3;
      const int chunk = (12 + ci) ^ ((row >> 3) & 7);
      const int base = buf ? ETI_OFF : ETU_OFF;
      *reinterpret_cast<short8*>(&S[base + row * ET_STRIDE + chunk * 8]) = z8;
    }
  }

  // weight stores to LDS
#pragma unroll
  for (int i = 0; i < 4; ++i)
    reinterpret_cast<short8*>(S)[tid + i * 448] = wtmp[i];
  __syncthreads();

  const int mrow = w * 16 + l15;  // this lane's row (m) across the whole MLP
  const int c = lane & 31, half = lane >> 5;
  const int* nbu = s_nb[0];
  const int* nbi = s_nb[1];

  // ---- issue ALL gathers for both sources (emb rows + scr frags) ----
  unsigned int evu[8], evi[8];
#pragma unroll
  for (int rr = 0; rr < 8; ++rr) {
    const int rbase = w + rr * 7;
    if (rbase < 50) {
      const int r = rbase * 2 + half;
      evu[rr] = *reinterpret_cast<const unsigned int*>(
          ws + EMBU_OFF + (size_t)nbu[r] * 64 + c * 2);
      evi[rr] = *reinterpret_cast<const unsigned int*>(
          ws + EMBI_OFF + (size_t)nbi[r] * 64 + c * 2);
    } else {
      evu[rr] = 0u; evi[rr] = 0u;
    }
  }
  short8 sbu[4], sbi[4];
  {
    const unsigned short* arow = ws + SCRU_OFF + (size_t)nbu[mrow] * 128;
#pragma unroll
    for (int k = 0; k < 4; ++k)
      sbu[k] = *reinterpret_cast<const short8*>(arow + k * 32 + quad * 8);
  }
  {
    const unsigned short* arow = ws + SCRI_OFF + (size_t)nbi[mrow] * 128;
#pragma unroll
    for (int k = 0; k < 4; ++k)
      sbi[k] = *reinterpret_cast<const short8*>(arow + k * 32 + quad * 8);
  }

  // ---- Et stores: u32-paired (shfl_xor across halves) + chunk swizzle ----
#pragma unroll
  for (int rr = 0; rr < 8; ++rr) {
    const int rbase = w + rr * 7;
    if (rbase < 50) {
      const int r0 = rbase * 2;
      const int p0 = ((r0 >> 5) << 5) | (((r0 >> 2) & 3) << 3) |
                     (((r0 >> 4) & 1) << 2) | (r0 & 3);  // even
      const int sw = ((c >> 2) & 7) << 3;  // = ((row>>3)&7)<<3 for both halves
      const int q = (2 * c + half) * ET_STRIDE + (p0 ^ sw);  // even hw offset
      unsigned int vu = evu[rr];
      unsigned int pu = __shfl_xor(vu, 32, 64);
      unsigned int du = half ? ((vu & 0xffff0000u) | (pu >> 16))
                             : ((vu & 0x0000ffffu) | (pu << 16));
      *reinterpret_cast<unsigned int*>(&S[ETU_OFF + q]) = du;
      unsigned int vi = evi[rr];
      unsigned int pi = __shfl_xor(vi, 32, 64);
      unsigned int di = half ? ((vi & 0xffff0000u) | (pi >> 16))
                             : ((vi & 0x0000ffffu) | (pi << 16));
      *reinterpret_cast<unsigned int*>(&S[ETI_OFF + q]) = di;
    }
  }
  __syncthreads();

  // ---- both pools back-to-back (no further barriers until the reduce) ----
  short8 x0, x1, x2, x3;
  pool_mfma(S + ETU_OFF, sbu, l15, quad, x0, x1);
  pool_mfma(S + ETI_OFF, sbi, l15, quad, x2, x3);

  // ---- MLP fully in registers; W1..W3 from LDS, W4 from global ----
  // L1: 128 -> 64
  f32x4 y[4];
#pragma unroll
  for (int po = 0; po < 4; ++po) y[po] = (f32x4){0.f, 0.f, 0.f, 0.f};
  {
    short8 xf[4] = {x0, x1, x2, x3};
#pragma unroll
    for (int k4 = 0; k4 < 4; ++k4)
#pragma unroll
      for (int po = 0; po < 4; ++po) {
        short8 wa = *reinterpret_cast<const short8*>(
            S + W1_OFF + ((po * 4 + k4) * 64 + lane) * 8);
        y[po] = __builtin_amdgcn_mfma_f32_16x16x32_bf16(wa, xf[k4], y[po], 0, 0, 0);
      }
  }
#pragma unroll
  for (int po = 0; po < 4; ++po) {
    const float4 bb = *reinterpret_cast<const float4*>(b1 + po * 16 + quad * 4);
#pragma unroll
    for (int r = 0; r < 4; ++r) y[po][r] = fmaxf(y[po][r] + bb[r], 0.f);
  }
  short8 g0 = pk2(y[0], y[1]), g1 = pk2(y[2], y[3]);

  // L2: 64 -> 64
  f32x4 v[4];
#pragma unroll
  for (int po = 0; po < 4; ++po) v[po] = (f32x4){0.f, 0.f, 0.f, 0.f};
#pragma unroll
  for (int k4 = 0; k4 < 2; ++k4) {
    short8 gf = k4 ? g1 : g0;
#pragma unroll
    for (int po = 0; po < 4; ++po) {
      short8 wa = *reinterpret_cast<const short8*>(
          S + W2_OFF + ((po * 2 + k4) * 64 + lane) * 8);
      v[po] = __builtin_amdgcn_mfma_f32_16x16x32_bf16(wa, gf, v[po], 0, 0, 0);
    }
  }
#pragma unroll
  for (int po = 0; po < 4; ++po) {
    const float4 bb = *reinterpret_cast<const float4*>(b2 + po * 16 + quad * 4);
#pragma unroll
    for (int r = 0; r < 4; ++r) v[po][r] = fmaxf(v[po][r] + bb[r], 0.f);
  }
  short8 h0 = pk2(v[0], v[1]), h1 = pk2(v[2], v[3]);

  // L3: 64 -> 32
  f32x4 t3[2];
  t3[0] = (f32x4){0.f, 0.f, 0.f, 0.f};
  t3[1] = (f32x4){0.f, 0.f, 0.f, 0.f};
#pragma unroll
  for (int k4 = 0; k4 < 2; ++k4) {
    short8 gf = k4 ? h1 : h0;
#pragma unroll
    for (int po = 0; po < 2; ++po) {
      short8 wa = *reinterpret_cast<const short8*>(
          S + W3_OFF + ((po * 2 + k4) * 64 + lane) * 8);
      t3[po] = __builtin_amdgcn_mfma_f32_16x16x32_bf16(wa, gf, t3[po], 0, 0, 0);
    }
  }
#pragma unroll
  for (int po = 0; po < 2; ++po) {
    const float4 bb = *reinterpret_cast<const float4*>(b3 + po * 16 + quad * 4);
#pragma unroll
    for (int r = 0; r < 4; ++r) t3[po][r] = fmaxf(t3[po][r] + bb[r], 0.f);
  }
  short8 q0 = pk2(t3[0], t3[1]);

  // L4: 32 -> 32 (weights from GLOBAL), fused with L5 + sigmoid + partial mean
  f32x4 u[2];
  u[0] = (f32x4){0.f, 0.f, 0.f, 0.f};
  u[1] = (f32x4){0.f, 0.f, 0.f, 0.f};
#pragma unroll
  for (int po = 0; po < 2; ++po) {
    short8 wa = *reinterpret_cast<const short8*>(ws + W4_OFF + (po * 64 + lane) * 8);
    u[po] = __builtin_amdgcn_mfma_f32_16x16x32_bf16(wa, q0, u[po], 0, 0, 0);
  }
  float part = 0.f;
#pragma unroll
  for (int po = 0; po < 2; ++po) {
    const float4 bb = *reinterpret_cast<const float4*>(b4 + po * 16 + quad * 4);
    const float4 wv = *reinterpret_cast<const float4*>(w5 + po * 16 + quad * 4);
#pragma unroll
    for (int r = 0; r < 4; ++r)
      part = fmaf(fmaxf(u[po][r] + bb[r], 0.f), wv[r], part);
  }
  // sum the 4 quad-partials for this m (lanes l15, l15+16, l15+32, l15+48)
  part += __shfl_xor(part, 16, 64);
  part += __shfl_xor(part, 32, 64);
  float sig = 1.f / (1.f + expf(-(part + b5[0])));
  if (mrow >= KN) sig = 0.f;
  // sum over the wave's 16 rows (each quad-group holds identical copies)
  sig += __shfl_xor(sig, 1, 64);
  sig += __shfl_xor(sig, 2, 64);
  sig += __shfl_xor(sig, 4, 64);
  sig += __shfl_xor(sig, 8, 64);
  if (lane == 0) s_red[w] = sig;
  __syncthreads();
  if (tid == 0) {
    float acc = 0.f;
#pragma unroll
    for (int i = 0; i < 7; ++i) acc += s_red[i];
    out[b] = acc * (1.0f / KN);
  }
}

extern "C" void kernel_launch(void* const* d_in, const int* in_sizes, int n_in,
                              void* d_out, int out_size, void* d_ws,
                              size_t ws_size, hipStream_t stream) {
  const float* user_emb = (const float*)d_in[0];
  const float* item_emb = (const float*)d_in[1];
  const float* user_scr = (const float*)d_in[2];
  const float* item_scr = (const float*)d_in[3];
  const float* w1 = (const float*)d_in[4];
  const float* b1 = (const float*)d_in[5];
  const float* w2 = (const float*)d_in[6];
  const float* b2 = (const float*)d_in[7];
  const float* w3 = (const float*)d_in[8];
  const float* b3 = (const float*)d_in[9];
  const float* w4 = (const float*)d_in[10];
  const float* b4 = (const float*)d_in[11];
  const float* w5 = (const float*)d_in[12];
  const float* b5 = (const float*)d_in[13];
  const int* user_idx_t = (const int*)d_in[14];
  const int* item_idx_t = (const int*)d_in[15];
  const int* user_idxs = (const int*)d_in[16];
  const int* item_idxs = (const int*)d_in[17];
  unsigned short* wsw = (unsigned short*)d_ws;

  // prep: 15360 (weights) + 2.4M (scr) + 1.2M (emb) threads
  prep<<<dim3((15360 + 2400000 + 1200000 + 255) / 256), dim3(256), 0, stream>>>(
      w1, w2, w3, w4, user_scr, item_scr, user_emb, item_emb, wsw);

  const int B = in_sizes[16];  // 8192
  cnn_mfma7<<<dim3(B), dim3(448), 0, stream>>>(
      wsw, b1, b2, b3, b4, w5, b5, user_idx_t, item_idx_t, user_idxs,
      item_idxs, (float*)d_out);
}